// Round 1
// baseline (157.106 us; speedup 1.0000x reference)
//
#include <hip/hip_runtime.h>
#include <cstddef>

#define S_LEN 4096
#define C_DIM 256
#define NHEADS 8
#define HDIM 32

typedef __attribute__((ext_vector_type(8))) _Float16 half8;
typedef __attribute__((ext_vector_type(4))) _Float16 half4;
typedef __attribute__((ext_vector_type(2))) _Float16 h2t;
typedef __attribute__((ext_vector_type(2))) __fp16 fp16x2;
typedef __attribute__((ext_vector_type(4))) float floatx4;

// scale * log2(e) folded into W_q and bias_q at prep time
#define SC2F ((float)(0.17677669529663687 * 1.4426950408889634))

// ---------------------------------------------------------------- prep + GN partial stats
__global__ __launch_bounds__(256) void prep_stats(
    const float* __restrict__ qkv_w, const float* __restrict__ proj_w,
    const float* __restrict__ qkv_b, const float* __restrict__ x,
    _Float16* __restrict__ wq, _Float16* __restrict__ wp,
    float* __restrict__ qbias, float* __restrict__ pstat)
{
  const int blk = blockIdx.x;
  const int tid = threadIdx.x;
  if (blk < 512) {
    __shared__ float red[2][4];
    const int gb = blk >> 3, e = blk & 7;       // gb = b*32+g
    const int g = gb & 31, b = gb >> 5;
    const float* xb = x + ((size_t)b * C_DIM + g * 8) * S_LEN + e * 4096;
    const float4* x4 = (const float4*)xb;       // 1024 float4
    float sum = 0.f, sumsq = 0.f;
    #pragma unroll
    for (int i = 0; i < 4; ++i) {
      float4 v = x4[tid + i * 256];
      sum += v.x + v.y + v.z + v.w;
      sumsq += v.x * v.x + v.y * v.y + v.z * v.z + v.w * v.w;
    }
    for (int off = 1; off < 64; off <<= 1) {
      sum += __shfl_xor(sum, off, 64);
      sumsq += __shfl_xor(sumsq, off, 64);
    }
    const int wv = tid >> 6, lane = tid & 63;
    if (lane == 0) { red[0][wv] = sum; red[1][wv] = sumsq; }
    __syncthreads();
    if (tid == 0) {
      pstat[(gb * 8 + e) * 2 + 0] = red[0][0] + red[0][1] + red[0][2] + red[0][3];
      pstat[(gb * 8 + e) * 2 + 1] = red[1][0] + red[1][1] + red[1][2] + red[1][3];
    }
  } else {
    int idx = (blk - 512) * 256 + tid;
    if (idx < 768 * 256) {
      float v = qkv_w[idx];
      if (idx < 256 * 256) v *= SC2F;          // q rows
      wq[idx] = (_Float16)v;
    } else if (idx < 768 * 256 + 256 * 256) {
      int i = idx - 768 * 256;
      wp[i] = (_Float16)proj_w[i];
    } else if (idx < 768 * 256 + 256 * 256 + 768) {
      int i = idx - (768 * 256 + 256 * 256);
      float bv = qkv_b[i];
      if (i < 256) bv *= SC2F;
      qbias[i] = bv;
    }
  }
}

// ---------------------------------------------------------------- QKV GEMM + inline GN
__global__ __launch_bounds__(256) void qkv_gn_gemm(
    const _Float16* __restrict__ W, const float* __restrict__ bias,
    const float* __restrict__ x, const float* __restrict__ gamma,
    const float* __restrict__ beta, const float* __restrict__ pstat,
    _Float16* __restrict__ qo, _Float16* __restrict__ ko_,
    _Float16* __restrict__ vo)
{
  __shared__ __align__(16) _Float16 Ld[64 * 264];   // [s][c], stride 264
  const int tid = threadIdx.x;
  const int b = blockIdx.z;
  const int s0 = blockIdx.y * 64;

  {  // ---- inline GN apply: x (c,s) -> Ld[s][c] f16
    const int c0 = (tid & 127) * 2, c1 = c0 + 1;
    const int sh = tid >> 7;                         // s-half 0/1
    const int g = c0 >> 3;
    const int gb = b * 32 + g;
    float s = 0.f, sq = 0.f;
    #pragma unroll
    for (int e = 0; e < 8; ++e) {
      s  += pstat[(gb * 8 + e) * 2 + 0];
      sq += pstat[(gb * 8 + e) * 2 + 1];
    }
    const float mean = s * (1.f / 32768.f);
    const float rstd = rsqrtf(sq * (1.f / 32768.f) - mean * mean + 1e-6f);
    const float ga0 = gamma[c0] * rstd, be0 = beta[c0] - mean * ga0;
    const float ga1 = gamma[c1] * rstd, be1 = beta[c1] - mean * ga1;
    const float4* xa = (const float4*)(x + ((size_t)b * C_DIM + c0) * S_LEN + s0 + sh * 32);
    const float4* xc = (const float4*)(x + ((size_t)b * C_DIM + c1) * S_LEN + s0 + sh * 32);
    #pragma unroll
    for (int j = 0; j < 8; ++j) {
      float4 a = xa[j], c = xc[j];
      int sl = sh * 32 + j * 4;
      *(h2t*)&Ld[(sl + 0) * 264 + c0] = (h2t){ (_Float16)(a.x * ga0 + be0), (_Float16)(c.x * ga1 + be1) };
      *(h2t*)&Ld[(sl + 1) * 264 + c0] = (h2t){ (_Float16)(a.y * ga0 + be0), (_Float16)(c.y * ga1 + be1) };
      *(h2t*)&Ld[(sl + 2) * 264 + c0] = (h2t){ (_Float16)(a.z * ga0 + be0), (_Float16)(c.z * ga1 + be1) };
      *(h2t*)&Ld[(sl + 3) * 264 + c0] = (h2t){ (_Float16)(a.w * ga0 + be0), (_Float16)(c.w * ga1 + be1) };
    }
  }
  __syncthreads();

  const int lane = tid & 63, wv = tid >> 6;
  const int m = lane & 15, quad = lane >> 4;
  const int mtb = blockIdx.x * 8 + wv * 2;      // 2 mt tiles per wave
  const _Float16* wrow0 = W + (size_t)((mtb + 0) * 16 + m) * C_DIM + quad * 8;
  const _Float16* wrow1 = W + (size_t)((mtb + 1) * 16 + m) * C_DIM + quad * 8;
  const _Float16* lp = &Ld[m * 264 + quad * 8];

  floatx4 acc[2][4];
  #pragma unroll
  for (int j = 0; j < 2; ++j)
    #pragma unroll
    for (int s = 0; s < 4; ++s) acc[j][s] = (floatx4){0.f,0.f,0.f,0.f};

  #pragma unroll
  for (int k0 = 0; k0 < C_DIM; k0 += 32) {
    half8 b0 = *(const half8*)(lp + k0);
    half8 b1 = *(const half8*)(lp + 16 * 264 + k0);
    half8 b2 = *(const half8*)(lp + 32 * 264 + k0);
    half8 b3 = *(const half8*)(lp + 48 * 264 + k0);
    half8 a0 = *(const half8*)(wrow0 + k0);
    half8 a1 = *(const half8*)(wrow1 + k0);
    acc[0][0] = __builtin_amdgcn_mfma_f32_16x16x32_f16(a0, b0, acc[0][0], 0, 0, 0);
    acc[0][1] = __builtin_amdgcn_mfma_f32_16x16x32_f16(a0, b1, acc[0][1], 0, 0, 0);
    acc[0][2] = __builtin_amdgcn_mfma_f32_16x16x32_f16(a0, b2, acc[0][2], 0, 0, 0);
    acc[0][3] = __builtin_amdgcn_mfma_f32_16x16x32_f16(a0, b3, acc[0][3], 0, 0, 0);
    acc[1][0] = __builtin_amdgcn_mfma_f32_16x16x32_f16(a1, b0, acc[1][0], 0, 0, 0);
    acc[1][1] = __builtin_amdgcn_mfma_f32_16x16x32_f16(a1, b1, acc[1][1], 0, 0, 0);
    acc[1][2] = __builtin_amdgcn_mfma_f32_16x16x32_f16(a1, b2, acc[1][2], 0, 0, 0);
    acc[1][3] = __builtin_amdgcn_mfma_f32_16x16x32_f16(a1, b3, acc[1][3], 0, 0, 0);
  }

  if (blockIdx.x < 4) {
    // ---- q/k epilogue: coalesced half4 stores
    #pragma unroll
    for (int j = 0; j < 2; ++j) {
      const int ob = (mtb + j) * 16 + quad * 4;
      const float bv0 = bias[ob], bv1 = bias[ob + 1],
                  bv2 = bias[ob + 2], bv3 = bias[ob + 3];
      #pragma unroll
      for (int sub = 0; sub < 4; ++sub) {
        int s = s0 + sub * 16 + m;
        half4 h = { (_Float16)(acc[j][sub][0] + bv0), (_Float16)(acc[j][sub][1] + bv1),
                    (_Float16)(acc[j][sub][2] + bv2), (_Float16)(acc[j][sub][3] + bv3) };
        _Float16* dst = (ob < 256) ? qo : ko_;
        int oo = ob & 255, n = oo >> 5, d0 = oo & 31;
        *(half4*)(dst + (((size_t)b * NHEADS + n) * S_LEN + s) * HDIM + d0) = h;
      }
    }
  } else {
    // ---- v epilogue via LDS: stage [128 ch][64 s] (stride 72), store 16B
    __syncthreads();                          // Ld b-frag reads complete
    _Float16* VLd = Ld;                       // reuse, 128*72*2B = 18.4 KB
    #pragma unroll
    for (int j = 0; j < 2; ++j) {
      const int ob = (mtb + j) * 16 + quad * 4;
      const int lch = (wv * 2 + j) * 16 + quad * 4;   // 0..127
      const float bv0 = bias[ob], bv1 = bias[ob + 1],
                  bv2 = bias[ob + 2], bv3 = bias[ob + 3];
      #pragma unroll
      for (int sub = 0; sub < 4; ++sub) {
        int s = sub * 16 + m;
        VLd[(lch + 0) * 72 + s] = (_Float16)(acc[j][sub][0] + bv0);
        VLd[(lch + 1) * 72 + s] = (_Float16)(acc[j][sub][1] + bv1);
        VLd[(lch + 2) * 72 + s] = (_Float16)(acc[j][sub][2] + bv2);
        VLd[(lch + 3) * 72 + s] = (_Float16)(acc[j][sub][3] + bv3);
      }
    }
    __syncthreads();
    const int lch = tid >> 1, sh = tid & 1;   // half-row per thread (32 halfs)
    const int oo = (blockIdx.x - 4) * 128 + lch;    // 0..255
    const int n = oo >> 5, d = oo & 31;
    _Float16* dst = vo + ((size_t)(b * NHEADS + n) * HDIM + d) * S_LEN + s0 + sh * 32;
    const _Float16* src = VLd + lch * 72 + sh * 32;
    *(half8*)(dst + 0)  = *(const half8*)(src + 0);
    *(half8*)(dst + 8)  = *(const half8*)(src + 8);
    *(half8*)(dst + 16) = *(const half8*)(src + 16);
    *(half8*)(dst + 24) = *(const half8*)(src + 24);
  }
}

// ---------------------------------------------------------------- Attention
// kh split 2 -> 4: grid 1024 blocks x 8 waves = 4 blocks/CU = 32 waves/CU
// (100% occupancy cap vs previous 50%). Each block: 256 q rows x 1024 keys.
__global__ __launch_bounds__(512) void attn_kernel(
    const _Float16* __restrict__ q, const _Float16* __restrict__ k,
    const _Float16* __restrict__ v, _Float16* __restrict__ po,
    float* __restrict__ pl)
{
  __shared__ __align__(16) _Float16 Kl[2][64 * 40];  // (kk, d) stride 40
  __shared__ __align__(16) _Float16 Vl[2][32 * 68];  // (d, kk) stride 68
  const int tid = threadIdx.x;
  const int lane = tid & 63, wv = tid >> 6;          // wv 0..7
  const int m = lane & 15, quad = lane >> 4;
  const int n = blockIdx.y, b = blockIdx.z;
  const int qc = blockIdx.x >> 2, kh = blockIdx.x & 3;
  const int q0 = qc * 256 + wv * 32;
  const int bh = b * NHEADS + n;

  const _Float16* qb = q + (size_t)bh * S_LEN * HDIM;
  const _Float16* kb = k + (size_t)bh * S_LEN * HDIM + (size_t)kh * 1024 * HDIM;
  const _Float16* vb = v + (size_t)bh * HDIM * S_LEN + (size_t)kh * 1024;

  // Q B-frags (QK): lane q=m holds d=quad*8+j; two 16-row tiles
  half8 qfA = *(const half8*)(qb + (size_t)(q0 + m) * HDIM + quad * 8);
  half8 qfB = *(const half8*)(qb + (size_t)(q0 + 16 + m) * HDIM + quad * 8);

  // staging: wave wv stages K rows [wv*8,+8), V rows [wv*4,+4); 8B per lane
  const int krow = wv * 8 + (lane >> 3), kc = (lane & 7) * 4;
  const int vrow = wv * 4 + (lane >> 4), vc = (lane & 15) * 4;
  const _Float16* kg = kb + (size_t)krow * HDIM + kc;
  const _Float16* vg = vb + (size_t)vrow * S_LEN + vc;
  const int klds = krow * 40 + kc;
  const int vlds = vrow * 68 + vc;

  int2 kreg = *(const int2*)kg;
  int2 vreg = *(const int2*)vg;
  const _Float16* kgp = kg + 64 * HDIM;
  const _Float16* vgp = vg + 64;

  floatx4 oA0 = {0.f,0.f,0.f,0.f}, oA1 = oA0, oB0 = oA0, oB1 = oA0;
  float lA = 0.f, lB = 0.f;
  const fp16x2 one2 = { (__fp16)1.0f, (__fp16)1.0f };

  #pragma unroll 2
  for (int it = 0; it < 16; ++it) {          // 16 x 64 keys = 1024 (quarter)
    const int bufi = it & 1;
    *(int2*)(&Kl[bufi][klds]) = kreg;
    *(int2*)(&Vl[bufi][vlds]) = vreg;
    kreg = *(const int2*)kgp; kgp += 64 * HDIM;   // unconditional prefetch
    vreg = *(const int2*)vgp; vgp += 64;
    __syncthreads();
    const _Float16* Kb = Kl[bufi];
    const _Float16* Vb = Vl[bufi];
    #pragma unroll
    for (int t = 0; t < 4; ++t) {
      half8 kf = *(const half8*)(Kb + (t * 16 + m) * 40 + quad * 8);
      half4 vf0 = *(const half4*)(Vb + m * 68 + t * 16 + quad * 4);
      half4 vf1 = *(const half4*)(Vb + (16 + m) * 68 + t * 16 + quad * 4);
      floatx4 z = {0.f,0.f,0.f,0.f};
      floatx4 sA = __builtin_amdgcn_mfma_f32_16x16x32_f16(kf, qfA, z, 0, 0, 0);
      floatx4 sB = __builtin_amdgcn_mfma_f32_16x16x32_f16(kf, qfB, z, 0, 0, 0);
      float eA0 = __builtin_amdgcn_exp2f(sA[0]);
      float eA1 = __builtin_amdgcn_exp2f(sA[1]);
      float eA2 = __builtin_amdgcn_exp2f(sA[2]);
      float eA3 = __builtin_amdgcn_exp2f(sA[3]);
      float eB0 = __builtin_amdgcn_exp2f(sB[0]);
      float eB1 = __builtin_amdgcn_exp2f(sB[1]);
      float eB2 = __builtin_amdgcn_exp2f(sB[2]);
      float eB3 = __builtin_amdgcn_exp2f(sB[3]);
      half4 pA, pB;
      fp16x2 pAlo = __builtin_amdgcn_cvt_pkrtz(eA0, eA1);
      fp16x2 pAhi = __builtin_amdgcn_cvt_pkrtz(eA2, eA3);
      fp16x2 pBlo = __builtin_amdgcn_cvt_pkrtz(eB0, eB1);
      fp16x2 pBhi = __builtin_amdgcn_cvt_pkrtz(eB2, eB3);
      *(fp16x2*)&pA = pAlo; *((fp16x2*)&pA + 1) = pAhi;
      *(fp16x2*)&pB = pBlo; *((fp16x2*)&pB + 1) = pBhi;
      lA = __builtin_amdgcn_fdot2(pAlo, one2, lA, false);
      lA = __builtin_amdgcn_fdot2(pAhi, one2, lA, false);
      lB = __builtin_amdgcn_fdot2(pBlo, one2, lB, false);
      lB = __builtin_amdgcn_fdot2(pBhi, one2, lB, false);
      oA0 = __builtin_amdgcn_mfma_f32_16x16x16f16(vf0, pA, oA0, 0, 0, 0);
      oA1 = __builtin_amdgcn_mfma_f32_16x16x16f16(vf1, pA, oA1, 0, 0, 0);
      oB0 = __builtin_amdgcn_mfma_f32_16x16x16f16(vf0, pB, oB0, 0, 0, 0);
      oB1 = __builtin_amdgcn_mfma_f32_16x16x16f16(vf1, pB, oB1, 0, 0, 0);
    }
  }
  // l split across 4 quads (keys) -> reduce
  lA += __shfl_xor(lA, 16, 64); lA += __shfl_xor(lA, 32, 64);
  lB += __shfl_xor(lB, 16, 64); lB += __shfl_xor(lB, 32, 64);
  // partial store (unnormalized): po[kh][bh][q][d] f16, pl[kh][bh*4096+q]
  _Float16* pobase = po + (size_t)kh * 2097152 + ((size_t)bh * S_LEN) * HDIM;
  {
    _Float16* poh = pobase + (size_t)(q0 + m) * HDIM;
    half4 h0 = { (_Float16)oA0[0], (_Float16)oA0[1], (_Float16)oA0[2], (_Float16)oA0[3] };
    half4 h1 = { (_Float16)oA1[0], (_Float16)oA1[1], (_Float16)oA1[2], (_Float16)oA1[3] };
    *(half4*)(poh + quad * 4) = h0;
    *(half4*)(poh + 16 + quad * 4) = h1;
    if (quad == 0) pl[(size_t)kh * 65536 + (size_t)bh * S_LEN + q0 + m] = lA;
  }
  {
    _Float16* poh = pobase + (size_t)(q0 + 16 + m) * HDIM;
    half4 h0 = { (_Float16)oB0[0], (_Float16)oB0[1], (_Float16)oB0[2], (_Float16)oB0[3] };
    half4 h1 = { (_Float16)oB1[0], (_Float16)oB1[1], (_Float16)oB1[2], (_Float16)oB1[3] };
    *(half4*)(poh + quad * 4) = h0;
    *(half4*)(poh + 16 + quad * 4) = h1;
    if (quad == 0) pl[(size_t)kh * 65536 + (size_t)bh * S_LEN + q0 + 16 + m] = lB;
  }
}

// ---------------------------------------------------------------- Proj GEMM (+ fused 4-way merge)
// s-tile 64 -> 32: grid (4,128,2) = 1024 blocks x 4 waves = 16 waves/CU
// (was 8). Merges the 4 kh partials.
__global__ __launch_bounds__(256) void proj_gemm(
    const _Float16* __restrict__ W, const float* __restrict__ bias,
    const _Float16* __restrict__ po, const float* __restrict__ pl,
    const float* __restrict__ x, float* __restrict__ out)
{
  __shared__ float Linv[256];                // [n][s_local 32]
  const int tid = threadIdx.x;
  const int lane = tid & 63, wv = tid >> 6;
  const int m = lane & 15, quad = lane >> 4;
  const int mt = blockIdx.x * 4 + wv;  // 0..15
  const int s0 = blockIdx.y * 32;
  const int b = blockIdx.z;
  const int row = mt * 16 + m;

  {
    const int nn = tid >> 5, jj = tid & 31;
    size_t base = (size_t)(b * NHEADS + nn) * S_LEN + s0 + jj;
    float a = pl[base] + pl[65536 + base] + pl[131072 + base] + pl[196608 + base];
    Linv[nn * 32 + jj] = 1.f / a;
  }
  __syncthreads();

  const _Float16* wrow = W + (size_t)row * C_DIM + quad * 8;
  floatx4 acc0 = {0.f,0.f,0.f,0.f}, acc1 = acc0;
  #pragma unroll
  for (int k0 = 0; k0 < C_DIM; k0 += 32) {
    const int n = k0 >> 5;
    const int d0 = quad * 8;
    half8 bf[2];
    #pragma unroll
    for (int sub = 0; sub < 2; ++sub) {
      size_t idx = (((size_t)(b * NHEADS + n)) * S_LEN + s0 + sub * 16 + m) * HDIM + d0;
      half8 a0 = *(const half8*)(po + idx);
      half8 a1 = *(const half8*)(po + 2097152 + idx);
      half8 a2 = *(const half8*)(po + 4194304 + idx);
      half8 a3 = *(const half8*)(po + 6291456 + idx);
      _Float16 iv = (_Float16)Linv[n * 32 + sub * 16 + m];
      bf[sub] = ((a0 + a1) + (a2 + a3)) * iv;
    }
    half8 af = *(const half8*)(wrow + k0);
    acc0 = __builtin_amdgcn_mfma_f32_16x16x32_f16(af, bf[0], acc0, 0, 0, 0);
    acc1 = __builtin_amdgcn_mfma_f32_16x16x32_f16(af, bf[1], acc1, 0, 0, 0);
  }
  floatx4 accs[2] = {acc0, acc1};
  #pragma unroll
  for (int sub = 0; sub < 2; ++sub) {
    int s = s0 + sub * 16 + m;
    #pragma unroll
    for (int r = 0; r < 4; ++r) {
      int c = mt * 16 + quad * 4 + r;
      size_t idx = ((size_t)b * C_DIM + c) * S_LEN + s;
      out[idx] = x[idx] + accs[sub][r] + bias[c];
    }
  }
}

// ---------------------------------------------------------------- launch
extern "C" void kernel_launch(void* const* d_in, const int* in_sizes, int n_in,
                              void* d_out, int out_size, void* d_ws, size_t ws_size,
                              hipStream_t stream) {
  const float* x        = (const float*)d_in[0];
  const float* gn_gamma = (const float*)d_in[1];
  const float* gn_beta  = (const float*)d_in[2];
  const float* qkv_w    = (const float*)d_in[3];
  const float* qkv_b    = (const float*)d_in[4];
  const float* proj_w   = (const float*)d_in[5];
  const float* proj_b   = (const float*)d_in[6];
  float* out = (float*)d_out;

  const size_t n1 = (size_t)2 * S_LEN * C_DIM;   // 2M elems = 4 MB f16
  char* ws = (char*)d_ws;
  _Float16* qx  = (_Float16*)ws;                 // (B,NH,S,hd)
  _Float16* kx  = qx + n1;                       // (B,NH,S,hd)
  _Float16* vx  = kx + n1;                       // (B,NH,hd,S)
  _Float16* wq  = vx + n1;                       // 768x256 f16
  _Float16* wp  = wq + 768 * 256;                // 256x256 f16
  float*    qbias = (float*)(wp + 256 * 256);    // 768 f32
  float*    pstat = qbias + 768;                 // 64*8*2 f32 = 4 KB
  _Float16* po  = (_Float16*)(pstat + 1024);     // 4 x 2M f16 = 16 MB
  float*    pl  = (float*)(po + 4 * n1);         // 4 x 64K f32 = 1 MB

  prep_stats<<<1539, 256, 0, stream>>>(qkv_w, proj_w, qkv_b, x, wq, wp, qbias, pstat);
  qkv_gn_gemm<<<dim3(6, 64, 2), 256, 0, stream>>>(wq, qbias, x, gn_gamma, gn_beta, pstat, qx, kx, vx);
  attn_kernel<<<dim3(64, 8, 2), 512, 0, stream>>>(qx, kx, vx, po, pl);
  proj_gemm<<<dim3(4, 128, 2), 256, 0, stream>>>(wp, proj_b, po, pl, x, out);
}

// Round 2
// 152.972 us; speedup vs baseline: 1.0270x; 1.0270x over previous
//
#include <hip/hip_runtime.h>
#include <cstddef>

#define S_LEN 4096
#define C_DIM 256
#define NHEADS 8
#define HDIM 32

typedef __attribute__((ext_vector_type(8))) _Float16 half8;
typedef __attribute__((ext_vector_type(4))) _Float16 half4;
typedef __attribute__((ext_vector_type(2))) _Float16 h2t;
typedef __attribute__((ext_vector_type(2))) __fp16 fp16x2;
typedef __attribute__((ext_vector_type(4))) float floatx4;

// scale * log2(e) folded into W_q and bias_q at prep time
#define SC2F ((float)(0.17677669529663687 * 1.4426950408889634))

// ---------------------------------------------------------------- prep + GN partial stats
__global__ __launch_bounds__(256) void prep_stats(
    const float* __restrict__ qkv_w, const float* __restrict__ proj_w,
    const float* __restrict__ qkv_b, const float* __restrict__ x,
    _Float16* __restrict__ wq, _Float16* __restrict__ wp,
    float* __restrict__ qbias, float* __restrict__ pstat)
{
  const int blk = blockIdx.x;
  const int tid = threadIdx.x;
  if (blk < 512) {
    __shared__ float red[2][4];
    const int gb = blk >> 3, e = blk & 7;       // gb = b*32+g
    const int g = gb & 31, b = gb >> 5;
    const float* xb = x + ((size_t)b * C_DIM + g * 8) * S_LEN + e * 4096;
    const float4* x4 = (const float4*)xb;       // 1024 float4
    float sum = 0.f, sumsq = 0.f;
    #pragma unroll
    for (int i = 0; i < 4; ++i) {
      float4 v = x4[tid + i * 256];
      sum += v.x + v.y + v.z + v.w;
      sumsq += v.x * v.x + v.y * v.y + v.z * v.z + v.w * v.w;
    }
    for (int off = 1; off < 64; off <<= 1) {
      sum += __shfl_xor(sum, off, 64);
      sumsq += __shfl_xor(sumsq, off, 64);
    }
    const int wv = tid >> 6, lane = tid & 63;
    if (lane == 0) { red[0][wv] = sum; red[1][wv] = sumsq; }
    __syncthreads();
    if (tid == 0) {
      pstat[(gb * 8 + e) * 2 + 0] = red[0][0] + red[0][1] + red[0][2] + red[0][3];
      pstat[(gb * 8 + e) * 2 + 1] = red[1][0] + red[1][1] + red[1][2] + red[1][3];
    }
  } else {
    int idx = (blk - 512) * 256 + tid;
    if (idx < 768 * 256) {
      float v = qkv_w[idx];
      if (idx < 256 * 256) v *= SC2F;          // q rows
      wq[idx] = (_Float16)v;
    } else if (idx < 768 * 256 + 256 * 256) {
      int i = idx - 768 * 256;
      wp[i] = (_Float16)proj_w[i];
    } else if (idx < 768 * 256 + 256 * 256 + 768) {
      int i = idx - (768 * 256 + 256 * 256);
      float bv = qkv_b[i];
      if (i < 256) bv *= SC2F;
      qbias[i] = bv;
    }
  }
}

// ---------------------------------------------------------------- QKV GEMM + inline GN
__global__ __launch_bounds__(256) void qkv_gn_gemm(
    const _Float16* __restrict__ W, const float* __restrict__ bias,
    const float* __restrict__ x, const float* __restrict__ gamma,
    const float* __restrict__ beta, const float* __restrict__ pstat,
    _Float16* __restrict__ qo, _Float16* __restrict__ ko_,
    _Float16* __restrict__ vo)
{
  __shared__ __align__(16) _Float16 Ld[64 * 264];   // [s][c], stride 264
  const int tid = threadIdx.x;
  const int b = blockIdx.z;
  const int s0 = blockIdx.y * 64;

  {  // ---- inline GN apply: x (c,s) -> Ld[s][c] f16
    const int c0 = (tid & 127) * 2, c1 = c0 + 1;
    const int sh = tid >> 7;                         // s-half 0/1
    const int g = c0 >> 3;
    const int gb = b * 32 + g;
    float s = 0.f, sq = 0.f;
    #pragma unroll
    for (int e = 0; e < 8; ++e) {
      s  += pstat[(gb * 8 + e) * 2 + 0];
      sq += pstat[(gb * 8 + e) * 2 + 1];
    }
    const float mean = s * (1.f / 32768.f);
    const float rstd = rsqrtf(sq * (1.f / 32768.f) - mean * mean + 1e-6f);
    const float ga0 = gamma[c0] * rstd, be0 = beta[c0] - mean * ga0;
    const float ga1 = gamma[c1] * rstd, be1 = beta[c1] - mean * ga1;
    const float4* xa = (const float4*)(x + ((size_t)b * C_DIM + c0) * S_LEN + s0 + sh * 32);
    const float4* xc = (const float4*)(x + ((size_t)b * C_DIM + c1) * S_LEN + s0 + sh * 32);
    #pragma unroll
    for (int j = 0; j < 8; ++j) {
      float4 a = xa[j], c = xc[j];
      int sl = sh * 32 + j * 4;
      *(h2t*)&Ld[(sl + 0) * 264 + c0] = (h2t){ (_Float16)(a.x * ga0 + be0), (_Float16)(c.x * ga1 + be1) };
      *(h2t*)&Ld[(sl + 1) * 264 + c0] = (h2t){ (_Float16)(a.y * ga0 + be0), (_Float16)(c.y * ga1 + be1) };
      *(h2t*)&Ld[(sl + 2) * 264 + c0] = (h2t){ (_Float16)(a.z * ga0 + be0), (_Float16)(c.z * ga1 + be1) };
      *(h2t*)&Ld[(sl + 3) * 264 + c0] = (h2t){ (_Float16)(a.w * ga0 + be0), (_Float16)(c.w * ga1 + be1) };
    }
  }
  __syncthreads();

  const int lane = tid & 63, wv = tid >> 6;
  const int m = lane & 15, quad = lane >> 4;
  const int mtb = blockIdx.x * 8 + wv * 2;      // 2 mt tiles per wave
  const _Float16* wrow0 = W + (size_t)((mtb + 0) * 16 + m) * C_DIM + quad * 8;
  const _Float16* wrow1 = W + (size_t)((mtb + 1) * 16 + m) * C_DIM + quad * 8;
  const _Float16* lp = &Ld[m * 264 + quad * 8];

  floatx4 acc[2][4];
  #pragma unroll
  for (int j = 0; j < 2; ++j)
    #pragma unroll
    for (int s = 0; s < 4; ++s) acc[j][s] = (floatx4){0.f,0.f,0.f,0.f};

  #pragma unroll
  for (int k0 = 0; k0 < C_DIM; k0 += 32) {
    half8 b0 = *(const half8*)(lp + k0);
    half8 b1 = *(const half8*)(lp + 16 * 264 + k0);
    half8 b2 = *(const half8*)(lp + 32 * 264 + k0);
    half8 b3 = *(const half8*)(lp + 48 * 264 + k0);
    half8 a0 = *(const half8*)(wrow0 + k0);
    half8 a1 = *(const half8*)(wrow1 + k0);
    acc[0][0] = __builtin_amdgcn_mfma_f32_16x16x32_f16(a0, b0, acc[0][0], 0, 0, 0);
    acc[0][1] = __builtin_amdgcn_mfma_f32_16x16x32_f16(a0, b1, acc[0][1], 0, 0, 0);
    acc[0][2] = __builtin_amdgcn_mfma_f32_16x16x32_f16(a0, b2, acc[0][2], 0, 0, 0);
    acc[0][3] = __builtin_amdgcn_mfma_f32_16x16x32_f16(a0, b3, acc[0][3], 0, 0, 0);
    acc[1][0] = __builtin_amdgcn_mfma_f32_16x16x32_f16(a1, b0, acc[1][0], 0, 0, 0);
    acc[1][1] = __builtin_amdgcn_mfma_f32_16x16x32_f16(a1, b1, acc[1][1], 0, 0, 0);
    acc[1][2] = __builtin_amdgcn_mfma_f32_16x16x32_f16(a1, b2, acc[1][2], 0, 0, 0);
    acc[1][3] = __builtin_amdgcn_mfma_f32_16x16x32_f16(a1, b3, acc[1][3], 0, 0, 0);
  }

  if (blockIdx.x < 4) {
    // ---- q/k epilogue: coalesced half4 stores
    #pragma unroll
    for (int j = 0; j < 2; ++j) {
      const int ob = (mtb + j) * 16 + quad * 4;
      const float bv0 = bias[ob], bv1 = bias[ob + 1],
                  bv2 = bias[ob + 2], bv3 = bias[ob + 3];
      #pragma unroll
      for (int sub = 0; sub < 4; ++sub) {
        int s = s0 + sub * 16 + m;
        half4 h = { (_Float16)(acc[j][sub][0] + bv0), (_Float16)(acc[j][sub][1] + bv1),
                    (_Float16)(acc[j][sub][2] + bv2), (_Float16)(acc[j][sub][3] + bv3) };
        _Float16* dst = (ob < 256) ? qo : ko_;
        int oo = ob & 255, n = oo >> 5, d0 = oo & 31;
        *(half4*)(dst + (((size_t)b * NHEADS + n) * S_LEN + s) * HDIM + d0) = h;
      }
    }
  } else {
    // ---- v epilogue via LDS: stage [128 ch][64 s] (stride 72), store 16B
    __syncthreads();                          // Ld b-frag reads complete
    _Float16* VLd = Ld;                       // reuse, 128*72*2B = 18.4 KB
    #pragma unroll
    for (int j = 0; j < 2; ++j) {
      const int ob = (mtb + j) * 16 + quad * 4;
      const int lch = (wv * 2 + j) * 16 + quad * 4;   // 0..127
      const float bv0 = bias[ob], bv1 = bias[ob + 1],
                  bv2 = bias[ob + 2], bv3 = bias[ob + 3];
      #pragma unroll
      for (int sub = 0; sub < 4; ++sub) {
        int s = sub * 16 + m;
        VLd[(lch + 0) * 72 + s] = (_Float16)(acc[j][sub][0] + bv0);
        VLd[(lch + 1) * 72 + s] = (_Float16)(acc[j][sub][1] + bv1);
        VLd[(lch + 2) * 72 + s] = (_Float16)(acc[j][sub][2] + bv2);
        VLd[(lch + 3) * 72 + s] = (_Float16)(acc[j][sub][3] + bv3);
      }
    }
    __syncthreads();
    const int lch = tid >> 1, sh = tid & 1;   // half-row per thread (32 halfs)
    const int oo = (blockIdx.x - 4) * 128 + lch;    // 0..255
    const int n = oo >> 5, d = oo & 31;
    _Float16* dst = vo + ((size_t)(b * NHEADS + n) * HDIM + d) * S_LEN + s0 + sh * 32;
    const _Float16* src = VLd + lch * 72 + sh * 32;
    *(half8*)(dst + 0)  = *(const half8*)(src + 0);
    *(half8*)(dst + 8)  = *(const half8*)(src + 8);
    *(half8*)(dst + 16) = *(const half8*)(src + 16);
    *(half8*)(dst + 24) = *(const half8*)(src + 24);
  }
}

// ---------------------------------------------------------------- Attention
// kh=2 (R0 grid: 512 blocks x 8 waves, 2 blocks/CU). R2 change: ILP
// restructure — batch-preload all 12 LDS fragments per 64-key tile so the
// scheduler can pipeline QK/softmax/PV across t-steps; VGPR budget raised
// to 128 via __launch_bounds__(512,4) (2 blocks/CU need only 4 waves/EU).
__global__ __launch_bounds__(512, 4) void attn_kernel(
    const _Float16* __restrict__ q, const _Float16* __restrict__ k,
    const _Float16* __restrict__ v, _Float16* __restrict__ po,
    float* __restrict__ pl)
{
  __shared__ __align__(16) _Float16 Kl[2][64 * 40];  // (kk, d) stride 40
  __shared__ __align__(16) _Float16 Vl[2][32 * 68];  // (d, kk) stride 68
  const int tid = threadIdx.x;
  const int lane = tid & 63, wv = tid >> 6;          // wv 0..7
  const int m = lane & 15, quad = lane >> 4;
  const int n = blockIdx.y, b = blockIdx.z;
  const int qc = blockIdx.x >> 1, kh = blockIdx.x & 1;
  const int q0 = qc * 256 + wv * 32;
  const int bh = b * NHEADS + n;

  const _Float16* qb = q + (size_t)bh * S_LEN * HDIM;
  const _Float16* kb = k + (size_t)bh * S_LEN * HDIM + (size_t)kh * 2048 * HDIM;
  const _Float16* vb = v + (size_t)bh * HDIM * S_LEN + (size_t)kh * 2048;

  // Q B-frags (QK): lane q=m holds d=quad*8+j; two 16-row tiles
  half8 qfA = *(const half8*)(qb + (size_t)(q0 + m) * HDIM + quad * 8);
  half8 qfB = *(const half8*)(qb + (size_t)(q0 + 16 + m) * HDIM + quad * 8);

  // staging: wave wv stages K rows [wv*8,+8), V rows [wv*4,+4); 8B per lane
  const int krow = wv * 8 + (lane >> 3), kc = (lane & 7) * 4;
  const int vrow = wv * 4 + (lane >> 4), vc = (lane & 15) * 4;
  const _Float16* kg = kb + (size_t)krow * HDIM + kc;
  const _Float16* vg = vb + (size_t)vrow * S_LEN + vc;
  const int klds = krow * 40 + kc;
  const int vlds = vrow * 68 + vc;

  int2 kreg = *(const int2*)kg;
  int2 vreg = *(const int2*)vg;
  const _Float16* kgp = kg + 64 * HDIM;
  const _Float16* vgp = vg + 64;

  floatx4 oA0 = {0.f,0.f,0.f,0.f}, oA1 = oA0, oB0 = oA0, oB1 = oA0;
  float lA0 = 0.f, lA1 = 0.f, lB0 = 0.f, lB1 = 0.f;
  const fp16x2 one2 = { (__fp16)1.0f, (__fp16)1.0f };
  const floatx4 zz = {0.f,0.f,0.f,0.f};

  #pragma unroll 2
  for (int it = 0; it < 32; ++it) {          // 32 x 64 keys = 2048 (half)
    const int bufi = it & 1;
    *(int2*)(&Kl[bufi][klds]) = kreg;
    *(int2*)(&Vl[bufi][vlds]) = vreg;
    kreg = *(const int2*)kgp; kgp += 64 * HDIM;   // unconditional prefetch
    vreg = *(const int2*)vgp; vgp += 64;
    __syncthreads();
    const _Float16* Kb = Kl[bufi];
    const _Float16* Vb = Vl[bufi];

    // batch-preload all LDS fragments for the 4 t-steps (12 ds_reads issue
    // together; fine-grained lgkmcnt lets compute start on kf[0])
    half8 kf[4]; half4 vf0[4], vf1[4];
    #pragma unroll
    for (int t = 0; t < 4; ++t) {
      kf[t]  = *(const half8*)(Kb + (t * 16 + m) * 40 + quad * 8);
      vf0[t] = *(const half4*)(Vb + m * 68 + t * 16 + quad * 4);
      vf1[t] = *(const half4*)(Vb + (16 + m) * 68 + t * 16 + quad * 4);
    }

    #pragma unroll
    for (int t = 0; t < 4; ++t) {
      floatx4 sA = __builtin_amdgcn_mfma_f32_16x16x32_f16(kf[t], qfA, zz, 0, 0, 0);
      floatx4 sB = __builtin_amdgcn_mfma_f32_16x16x32_f16(kf[t], qfB, zz, 0, 0, 0);
      float eA0 = __builtin_amdgcn_exp2f(sA[0]);
      float eA1 = __builtin_amdgcn_exp2f(sA[1]);
      float eA2 = __builtin_amdgcn_exp2f(sA[2]);
      float eA3 = __builtin_amdgcn_exp2f(sA[3]);
      float eB0 = __builtin_amdgcn_exp2f(sB[0]);
      float eB1 = __builtin_amdgcn_exp2f(sB[1]);
      float eB2 = __builtin_amdgcn_exp2f(sB[2]);
      float eB3 = __builtin_amdgcn_exp2f(sB[3]);
      half4 pA, pB;
      fp16x2 pAlo = __builtin_amdgcn_cvt_pkrtz(eA0, eA1);
      fp16x2 pAhi = __builtin_amdgcn_cvt_pkrtz(eA2, eA3);
      fp16x2 pBlo = __builtin_amdgcn_cvt_pkrtz(eB0, eB1);
      fp16x2 pBhi = __builtin_amdgcn_cvt_pkrtz(eB2, eB3);
      *(fp16x2*)&pA = pAlo; *((fp16x2*)&pA + 1) = pAhi;
      *(fp16x2*)&pB = pBlo; *((fp16x2*)&pB + 1) = pBhi;
      lA0 = __builtin_amdgcn_fdot2(pAlo, one2, lA0, false);
      lA1 = __builtin_amdgcn_fdot2(pAhi, one2, lA1, false);
      lB0 = __builtin_amdgcn_fdot2(pBlo, one2, lB0, false);
      lB1 = __builtin_amdgcn_fdot2(pBhi, one2, lB1, false);
      oA0 = __builtin_amdgcn_mfma_f32_16x16x16f16(vf0[t], pA, oA0, 0, 0, 0);
      oA1 = __builtin_amdgcn_mfma_f32_16x16x16f16(vf1[t], pA, oA1, 0, 0, 0);
      oB0 = __builtin_amdgcn_mfma_f32_16x16x16f16(vf0[t], pB, oB0, 0, 0, 0);
      oB1 = __builtin_amdgcn_mfma_f32_16x16x16f16(vf1[t], pB, oB1, 0, 0, 0);
    }
  }
  float lA = lA0 + lA1, lB = lB0 + lB1;
  // l split across 4 quads (keys) -> reduce
  lA += __shfl_xor(lA, 16, 64); lA += __shfl_xor(lA, 32, 64);
  lB += __shfl_xor(lB, 16, 64); lB += __shfl_xor(lB, 32, 64);
  // partial store (unnormalized): po[kh][bh][q][d] f16, pl[kh][bh*4096+q]
  _Float16* pobase = po + (size_t)kh * 2097152 + ((size_t)bh * S_LEN) * HDIM;
  {
    _Float16* poh = pobase + (size_t)(q0 + m) * HDIM;
    half4 h0 = { (_Float16)oA0[0], (_Float16)oA0[1], (_Float16)oA0[2], (_Float16)oA0[3] };
    half4 h1 = { (_Float16)oA1[0], (_Float16)oA1[1], (_Float16)oA1[2], (_Float16)oA1[3] };
    *(half4*)(poh + quad * 4) = h0;
    *(half4*)(poh + 16 + quad * 4) = h1;
    if (quad == 0) pl[(size_t)kh * 65536 + (size_t)bh * S_LEN + q0 + m] = lA;
  }
  {
    _Float16* poh = pobase + (size_t)(q0 + 16 + m) * HDIM;
    half4 h0 = { (_Float16)oB0[0], (_Float16)oB0[1], (_Float16)oB0[2], (_Float16)oB0[3] };
    half4 h1 = { (_Float16)oB1[0], (_Float16)oB1[1], (_Float16)oB1[2], (_Float16)oB1[3] };
    *(half4*)(poh + quad * 4) = h0;
    *(half4*)(poh + 16 + quad * 4) = h1;
    if (quad == 0) pl[(size_t)kh * 65536 + (size_t)bh * S_LEN + q0 + 16 + m] = lB;
  }
}

// ---------------------------------------------------------------- Proj GEMM (+ fused merge)
__global__ __launch_bounds__(256) void proj_gemm(
    const _Float16* __restrict__ W, const float* __restrict__ bias,
    const _Float16* __restrict__ po, const float* __restrict__ pl,
    const float* __restrict__ x, float* __restrict__ out)
{
  __shared__ float Linv[512];                // [n][s_local 64]
  const int tid = threadIdx.x;
  const int lane = tid & 63, wv = tid >> 6;
  const int m = lane & 15, quad = lane >> 4;
  const int mt = blockIdx.x * 4 + wv;  // 0..15
  const int s0 = blockIdx.y * 64;
  const int b = blockIdx.z;
  const int row = mt * 16 + m;

  {
    const int nn = tid >> 5, jj = (tid & 31) * 2;
    size_t base = (size_t)(b * NHEADS + nn) * S_LEN + s0 + jj;
    float a0 = pl[base]     + pl[65536 + base];
    float a1 = pl[base + 1] + pl[65536 + base + 1];
    Linv[nn * 64 + jj]     = 1.f / a0;
    Linv[nn * 64 + jj + 1] = 1.f / a1;
  }
  __syncthreads();

  const _Float16* wrow = W + (size_t)row * C_DIM + quad * 8;
  floatx4 acc0 = {0.f,0.f,0.f,0.f}, acc1 = acc0, acc2 = acc0, acc3 = acc0;
  #pragma unroll
  for (int k0 = 0; k0 < C_DIM; k0 += 32) {
    const int n = k0 >> 5;
    const int d0 = quad * 8;
    half8 bf[4];
    #pragma unroll
    for (int sub = 0; sub < 4; ++sub) {
      size_t idx = (((size_t)(b * NHEADS + n)) * S_LEN + s0 + sub * 16 + m) * HDIM + d0;
      half8 a = *(const half8*)(po + idx);
      half8 c = *(const half8*)(po + 2097152 + idx);
      _Float16 iv = (_Float16)Linv[n * 64 + sub * 16 + m];
      bf[sub] = (a + c) * iv;
    }
    half8 af = *(const half8*)(wrow + k0);
    acc0 = __builtin_amdgcn_mfma_f32_16x16x32_f16(af, bf[0], acc0, 0, 0, 0);
    acc1 = __builtin_amdgcn_mfma_f32_16x16x32_f16(af, bf[1], acc1, 0, 0, 0);
    acc2 = __builtin_amdgcn_mfma_f32_16x16x32_f16(af, bf[2], acc2, 0, 0, 0);
    acc3 = __builtin_amdgcn_mfma_f32_16x16x32_f16(af, bf[3], acc3, 0, 0, 0);
  }
  floatx4 accs[4] = {acc0, acc1, acc2, acc3};
  #pragma unroll
  for (int sub = 0; sub < 4; ++sub) {
    int s = s0 + sub * 16 + m;
    #pragma unroll
    for (int r = 0; r < 4; ++r) {
      int c = mt * 16 + quad * 4 + r;
      size_t idx = ((size_t)b * C_DIM + c) * S_LEN + s;
      out[idx] = x[idx] + accs[sub][r] + bias[c];
    }
  }
}

// ---------------------------------------------------------------- launch
extern "C" void kernel_launch(void* const* d_in, const int* in_sizes, int n_in,
                              void* d_out, int out_size, void* d_ws, size_t ws_size,
                              hipStream_t stream) {
  const float* x        = (const float*)d_in[0];
  const float* gn_gamma = (const float*)d_in[1];
  const float* gn_beta  = (const float*)d_in[2];
  const float* qkv_w    = (const float*)d_in[3];
  const float* qkv_b    = (const float*)d_in[4];
  const float* proj_w   = (const float*)d_in[5];
  const float* proj_b   = (const float*)d_in[6];
  float* out = (float*)d_out;

  const size_t n1 = (size_t)2 * S_LEN * C_DIM;   // 2M elems = 4 MB f16
  char* ws = (char*)d_ws;
  _Float16* qx  = (_Float16*)ws;                 // (B,NH,S,hd)
  _Float16* kx  = qx + n1;                       // (B,NH,S,hd)
  _Float16* vx  = kx + n1;                       // (B,NH,hd,S)
  _Float16* wq  = vx + n1;                       // 768x256 f16
  _Float16* wp  = wq + 768 * 256;                // 256x256 f16
  float*    qbias = (float*)(wp + 256 * 256);    // 768 f32
  float*    pstat = qbias + 768;                 // 64*8*2 f32 = 4 KB
  _Float16* po  = (_Float16*)(pstat + 1024);     // 2 x 2M f16 = 8 MB
  float*    pl  = (float*)(po + 2 * n1);         // 2 x 64K f32 = 512 KB

  prep_stats<<<1539, 256, 0, stream>>>(qkv_w, proj_w, qkv_b, x, wq, wp, qbias, pstat);
  qkv_gn_gemm<<<dim3(6, 64, 2), 256, 0, stream>>>(wq, qbias, x, gn_gamma, gn_beta, pstat, qx, kx, vx);
  attn_kernel<<<dim3(32, 8, 2), 512, 0, stream>>>(qx, kx, vx, po, pl);
  proj_gemm<<<dim3(4, 64, 2), 256, 0, stream>>>(wp, proj_b, po, pl, x, out);
}

// Round 3
// 148.330 us; speedup vs baseline: 1.0592x; 1.0313x over previous
//
#include <hip/hip_runtime.h>
#include <cstddef>

#define S_LEN 4096
#define C_DIM 256
#define NHEADS 8
#define HDIM 32

typedef __attribute__((ext_vector_type(8))) _Float16 half8;
typedef __attribute__((ext_vector_type(4))) _Float16 half4;
typedef __attribute__((ext_vector_type(2))) _Float16 h2t;
typedef __attribute__((ext_vector_type(2))) __fp16 fp16x2;
typedef __attribute__((ext_vector_type(4))) float floatx4;

// scale * log2(e) folded into W_q and bias_q at prep time
#define SC2F ((float)(0.17677669529663687 * 1.4426950408889634))

// ---------------------------------------------------------------- prep + GN partial stats
__global__ __launch_bounds__(256) void prep_stats(
    const float* __restrict__ qkv_w, const float* __restrict__ proj_w,
    const float* __restrict__ qkv_b, const float* __restrict__ x,
    _Float16* __restrict__ wq, _Float16* __restrict__ wp,
    float* __restrict__ qbias, float* __restrict__ pstat)
{
  const int blk = blockIdx.x;
  const int tid = threadIdx.x;
  if (blk < 512) {
    __shared__ float red[2][4];
    const int gb = blk >> 3, e = blk & 7;       // gb = b*32+g
    const int g = gb & 31, b = gb >> 5;
    const float* xb = x + ((size_t)b * C_DIM + g * 8) * S_LEN + e * 4096;
    const float4* x4 = (const float4*)xb;       // 1024 float4
    float sum = 0.f, sumsq = 0.f;
    #pragma unroll
    for (int i = 0; i < 4; ++i) {
      float4 v = x4[tid + i * 256];
      sum += v.x + v.y + v.z + v.w;
      sumsq += v.x * v.x + v.y * v.y + v.z * v.z + v.w * v.w;
    }
    for (int off = 1; off < 64; off <<= 1) {
      sum += __shfl_xor(sum, off, 64);
      sumsq += __shfl_xor(sumsq, off, 64);
    }
    const int wv = tid >> 6, lane = tid & 63;
    if (lane == 0) { red[0][wv] = sum; red[1][wv] = sumsq; }
    __syncthreads();
    if (tid == 0) {
      pstat[(gb * 8 + e) * 2 + 0] = red[0][0] + red[0][1] + red[0][2] + red[0][3];
      pstat[(gb * 8 + e) * 2 + 1] = red[1][0] + red[1][1] + red[1][2] + red[1][3];
    }
  } else {
    int idx = (blk - 512) * 256 + tid;
    if (idx < 768 * 256) {
      float v = qkv_w[idx];
      if (idx < 256 * 256) v *= SC2F;          // q rows
      wq[idx] = (_Float16)v;
    } else if (idx < 768 * 256 + 256 * 256) {
      int i = idx - 768 * 256;
      wp[i] = (_Float16)proj_w[i];
    } else if (idx < 768 * 256 + 256 * 256 + 768) {
      int i = idx - (768 * 256 + 256 * 256);
      float bv = qkv_b[i];
      if (i < 256) bv *= SC2F;
      qbias[i] = bv;
    }
  }
}

// ---------------------------------------------------------------- QKV GEMM + inline GN
__global__ __launch_bounds__(256) void qkv_gn_gemm(
    const _Float16* __restrict__ W, const float* __restrict__ bias,
    const float* __restrict__ x, const float* __restrict__ gamma,
    const float* __restrict__ beta, const float* __restrict__ pstat,
    _Float16* __restrict__ qo, _Float16* __restrict__ ko_,
    _Float16* __restrict__ vo)
{
  __shared__ __align__(16) _Float16 Ld[64 * 264];   // [s][c], stride 264
  const int tid = threadIdx.x;
  const int b = blockIdx.z;
  const int s0 = blockIdx.y * 64;

  {  // ---- inline GN apply: x (c,s) -> Ld[s][c] f16
    const int c0 = (tid & 127) * 2, c1 = c0 + 1;
    const int sh = tid >> 7;                         // s-half 0/1
    const int g = c0 >> 3;
    const int gb = b * 32 + g;
    float s = 0.f, sq = 0.f;
    #pragma unroll
    for (int e = 0; e < 8; ++e) {
      s  += pstat[(gb * 8 + e) * 2 + 0];
      sq += pstat[(gb * 8 + e) * 2 + 1];
    }
    const float mean = s * (1.f / 32768.f);
    const float rstd = rsqrtf(sq * (1.f / 32768.f) - mean * mean + 1e-6f);
    const float ga0 = gamma[c0] * rstd, be0 = beta[c0] - mean * ga0;
    const float ga1 = gamma[c1] * rstd, be1 = beta[c1] - mean * ga1;
    const float4* xa = (const float4*)(x + ((size_t)b * C_DIM + c0) * S_LEN + s0 + sh * 32);
    const float4* xc = (const float4*)(x + ((size_t)b * C_DIM + c1) * S_LEN + s0 + sh * 32);
    #pragma unroll
    for (int j = 0; j < 8; ++j) {
      float4 a = xa[j], c = xc[j];
      int sl = sh * 32 + j * 4;
      *(h2t*)&Ld[(sl + 0) * 264 + c0] = (h2t){ (_Float16)(a.x * ga0 + be0), (_Float16)(c.x * ga1 + be1) };
      *(h2t*)&Ld[(sl + 1) * 264 + c0] = (h2t){ (_Float16)(a.y * ga0 + be0), (_Float16)(c.y * ga1 + be1) };
      *(h2t*)&Ld[(sl + 2) * 264 + c0] = (h2t){ (_Float16)(a.z * ga0 + be0), (_Float16)(c.z * ga1 + be1) };
      *(h2t*)&Ld[(sl + 3) * 264 + c0] = (h2t){ (_Float16)(a.w * ga0 + be0), (_Float16)(c.w * ga1 + be1) };
    }
  }
  __syncthreads();

  const int lane = tid & 63, wv = tid >> 6;
  const int m = lane & 15, quad = lane >> 4;
  const int mtb = blockIdx.x * 8 + wv * 2;      // 2 mt tiles per wave
  const _Float16* wrow0 = W + (size_t)((mtb + 0) * 16 + m) * C_DIM + quad * 8;
  const _Float16* wrow1 = W + (size_t)((mtb + 1) * 16 + m) * C_DIM + quad * 8;
  const _Float16* lp = &Ld[m * 264 + quad * 8];

  floatx4 acc[2][4];
  #pragma unroll
  for (int j = 0; j < 2; ++j)
    #pragma unroll
    for (int s = 0; s < 4; ++s) acc[j][s] = (floatx4){0.f,0.f,0.f,0.f};

  #pragma unroll
  for (int k0 = 0; k0 < C_DIM; k0 += 32) {
    half8 b0 = *(const half8*)(lp + k0);
    half8 b1 = *(const half8*)(lp + 16 * 264 + k0);
    half8 b2 = *(const half8*)(lp + 32 * 264 + k0);
    half8 b3 = *(const half8*)(lp + 48 * 264 + k0);
    half8 a0 = *(const half8*)(wrow0 + k0);
    half8 a1 = *(const half8*)(wrow1 + k0);
    acc[0][0] = __builtin_amdgcn_mfma_f32_16x16x32_f16(a0, b0, acc[0][0], 0, 0, 0);
    acc[0][1] = __builtin_amdgcn_mfma_f32_16x16x32_f16(a0, b1, acc[0][1], 0, 0, 0);
    acc[0][2] = __builtin_amdgcn_mfma_f32_16x16x32_f16(a0, b2, acc[0][2], 0, 0, 0);
    acc[0][3] = __builtin_amdgcn_mfma_f32_16x16x32_f16(a0, b3, acc[0][3], 0, 0, 0);
    acc[1][0] = __builtin_amdgcn_mfma_f32_16x16x32_f16(a1, b0, acc[1][0], 0, 0, 0);
    acc[1][1] = __builtin_amdgcn_mfma_f32_16x16x32_f16(a1, b1, acc[1][1], 0, 0, 0);
    acc[1][2] = __builtin_amdgcn_mfma_f32_16x16x32_f16(a1, b2, acc[1][2], 0, 0, 0);
    acc[1][3] = __builtin_amdgcn_mfma_f32_16x16x32_f16(a1, b3, acc[1][3], 0, 0, 0);
  }

  if (blockIdx.x < 4) {
    // ---- q/k epilogue: coalesced half4 stores
    #pragma unroll
    for (int j = 0; j < 2; ++j) {
      const int ob = (mtb + j) * 16 + quad * 4;
      const float bv0 = bias[ob], bv1 = bias[ob + 1],
                  bv2 = bias[ob + 2], bv3 = bias[ob + 3];
      #pragma unroll
      for (int sub = 0; sub < 4; ++sub) {
        int s = s0 + sub * 16 + m;
        half4 h = { (_Float16)(acc[j][sub][0] + bv0), (_Float16)(acc[j][sub][1] + bv1),
                    (_Float16)(acc[j][sub][2] + bv2), (_Float16)(acc[j][sub][3] + bv3) };
        _Float16* dst = (ob < 256) ? qo : ko_;
        int oo = ob & 255, n = oo >> 5, d0 = oo & 31;
        *(half4*)(dst + (((size_t)b * NHEADS + n) * S_LEN + s) * HDIM + d0) = h;
      }
    }
  } else {
    // ---- v epilogue via LDS: stage [128 ch][64 s] (stride 72), store 16B
    __syncthreads();                          // Ld b-frag reads complete
    _Float16* VLd = Ld;                       // reuse, 128*72*2B = 18.4 KB
    #pragma unroll
    for (int j = 0; j < 2; ++j) {
      const int ob = (mtb + j) * 16 + quad * 4;
      const int lch = (wv * 2 + j) * 16 + quad * 4;   // 0..127
      const float bv0 = bias[ob], bv1 = bias[ob + 1],
                  bv2 = bias[ob + 2], bv3 = bias[ob + 3];
      #pragma unroll
      for (int sub = 0; sub < 4; ++sub) {
        int s = sub * 16 + m;
        VLd[(lch + 0) * 72 + s] = (_Float16)(acc[j][sub][0] + bv0);
        VLd[(lch + 1) * 72 + s] = (_Float16)(acc[j][sub][1] + bv1);
        VLd[(lch + 2) * 72 + s] = (_Float16)(acc[j][sub][2] + bv2);
        VLd[(lch + 3) * 72 + s] = (_Float16)(acc[j][sub][3] + bv3);
      }
    }
    __syncthreads();
    const int lch = tid >> 1, sh = tid & 1;   // half-row per thread (32 halfs)
    const int oo = (blockIdx.x - 4) * 128 + lch;    // 0..255
    const int n = oo >> 5, d = oo & 31;
    _Float16* dst = vo + ((size_t)(b * NHEADS + n) * HDIM + d) * S_LEN + s0 + sh * 32;
    const _Float16* src = VLd + lch * 72 + sh * 32;
    *(half8*)(dst + 0)  = *(const half8*)(src + 0);
    *(half8*)(dst + 8)  = *(const half8*)(src + 8);
    *(half8*)(dst + 16) = *(const half8*)(src + 16);
    *(half8*)(dst + 24) = *(const half8*)(src + 24);
  }
}

// ---------------------------------------------------------------- Attention
// R3: anti-convoy restructure. 128-key tiles (16 barriers instead of 32),
// 8 independent 16-key sub-steps processed in per-wave rotated order
// ((t+wv)&7) so the 8 waves occupy different pipe phases simultaneously;
// s_setprio(1) around MFMA clusters (T5) reinforces cross-wave overlap.
__global__ __launch_bounds__(512) void attn_kernel(
    const _Float16* __restrict__ q, const _Float16* __restrict__ k,
    const _Float16* __restrict__ v, _Float16* __restrict__ po,
    float* __restrict__ pl)
{
  __shared__ __align__(16) _Float16 Kl[2][128 * 40];  // (kk, d) stride 40
  __shared__ __align__(16) _Float16 Vl[2][32 * 136];  // (d, kk) stride 136
  const int tid = threadIdx.x;
  const int lane = tid & 63, wv = tid >> 6;          // wv 0..7
  const int m = lane & 15, quad = lane >> 4;
  const int n = blockIdx.y, b = blockIdx.z;
  const int qc = blockIdx.x >> 1, kh = blockIdx.x & 1;
  const int q0 = qc * 256 + wv * 32;
  const int bh = b * NHEADS + n;

  const _Float16* qb = q + (size_t)bh * S_LEN * HDIM;
  const _Float16* kb = k + (size_t)bh * S_LEN * HDIM + (size_t)kh * 2048 * HDIM;
  const _Float16* vb = v + (size_t)bh * HDIM * S_LEN + (size_t)kh * 2048;

  // Q B-frags (QK): lane q=m holds d=quad*8+j; two 16-row tiles
  half8 qfA = *(const half8*)(qb + (size_t)(q0 + m) * HDIM + quad * 8);
  half8 qfB = *(const half8*)(qb + (size_t)(q0 + 16 + m) * HDIM + quad * 8);

  // staging (128-key tile): wave wv stages K rows [wv*16,+16), V d-rows
  // [wv*4,+4); 16B per lane per array
  const int krow = wv * 16 + (lane >> 2), kc = (lane & 3) * 8;
  const int vrow = wv * 4 + (lane >> 4), vc = (lane & 15) * 8;
  const _Float16* kg = kb + (size_t)krow * HDIM + kc;
  const _Float16* vg = vb + (size_t)vrow * S_LEN + vc;
  const int klds = krow * 40 + kc;
  const int vlds = vrow * 136 + vc;

  int4 kreg = *(const int4*)kg;
  int4 vreg = *(const int4*)vg;
  const _Float16* kgp = kg + 128 * HDIM;
  const _Float16* vgp = vg + 128;

  floatx4 oA0 = {0.f,0.f,0.f,0.f}, oA1 = oA0, oB0 = oA0, oB1 = oA0;
  float lA0 = 0.f, lA1 = 0.f, lB0 = 0.f, lB1 = 0.f;
  const fp16x2 one2 = { (__fp16)1.0f, (__fp16)1.0f };
  const floatx4 zz = {0.f,0.f,0.f,0.f};

  #pragma unroll 2
  for (int it = 0; it < 16; ++it) {          // 16 x 128 keys = 2048 (half)
    const int bufi = it & 1;
    *(int4*)(&Kl[bufi][klds]) = kreg;
    *(int4*)(&Vl[bufi][vlds]) = vreg;
    kreg = *(const int4*)kgp; kgp += 128 * HDIM;   // unconditional prefetch
    vreg = *(const int4*)vgp; vgp += 128;
    __syncthreads();
    const _Float16* Kb = Kl[bufi];
    const _Float16* Vb = Vl[bufi];

    #pragma unroll
    for (int t = 0; t < 8; ++t) {
      const int tt = (t + wv) & 7;           // per-wave phase rotation
      half8 kf  = *(const half8*)(Kb + (tt * 16 + m) * 40 + quad * 8);
      half4 vf0 = *(const half4*)(Vb + m * 136 + tt * 16 + quad * 4);
      half4 vf1 = *(const half4*)(Vb + (16 + m) * 136 + tt * 16 + quad * 4);
      __builtin_amdgcn_s_setprio(1);
      floatx4 sA = __builtin_amdgcn_mfma_f32_16x16x32_f16(kf, qfA, zz, 0, 0, 0);
      floatx4 sB = __builtin_amdgcn_mfma_f32_16x16x32_f16(kf, qfB, zz, 0, 0, 0);
      __builtin_amdgcn_s_setprio(0);
      float eA0 = __builtin_amdgcn_exp2f(sA[0]);
      float eA1 = __builtin_amdgcn_exp2f(sA[1]);
      float eA2 = __builtin_amdgcn_exp2f(sA[2]);
      float eA3 = __builtin_amdgcn_exp2f(sA[3]);
      float eB0 = __builtin_amdgcn_exp2f(sB[0]);
      float eB1 = __builtin_amdgcn_exp2f(sB[1]);
      float eB2 = __builtin_amdgcn_exp2f(sB[2]);
      float eB3 = __builtin_amdgcn_exp2f(sB[3]);
      half4 pA, pB;
      fp16x2 pAlo = __builtin_amdgcn_cvt_pkrtz(eA0, eA1);
      fp16x2 pAhi = __builtin_amdgcn_cvt_pkrtz(eA2, eA3);
      fp16x2 pBlo = __builtin_amdgcn_cvt_pkrtz(eB0, eB1);
      fp16x2 pBhi = __builtin_amdgcn_cvt_pkrtz(eB2, eB3);
      *(fp16x2*)&pA = pAlo; *((fp16x2*)&pA + 1) = pAhi;
      *(fp16x2*)&pB = pBlo; *((fp16x2*)&pB + 1) = pBhi;
      lA0 = __builtin_amdgcn_fdot2(pAlo, one2, lA0, false);
      lA1 = __builtin_amdgcn_fdot2(pAhi, one2, lA1, false);
      lB0 = __builtin_amdgcn_fdot2(pBlo, one2, lB0, false);
      lB1 = __builtin_amdgcn_fdot2(pBhi, one2, lB1, false);
      __builtin_amdgcn_s_setprio(1);
      oA0 = __builtin_amdgcn_mfma_f32_16x16x16f16(vf0, pA, oA0, 0, 0, 0);
      oA1 = __builtin_amdgcn_mfma_f32_16x16x16f16(vf1, pA, oA1, 0, 0, 0);
      oB0 = __builtin_amdgcn_mfma_f32_16x16x16f16(vf0, pB, oB0, 0, 0, 0);
      oB1 = __builtin_amdgcn_mfma_f32_16x16x16f16(vf1, pB, oB1, 0, 0, 0);
      __builtin_amdgcn_s_setprio(0);
    }
  }
  float lA = lA0 + lA1, lB = lB0 + lB1;
  // l split across 4 quads (keys) -> reduce
  lA += __shfl_xor(lA, 16, 64); lA += __shfl_xor(lA, 32, 64);
  lB += __shfl_xor(lB, 16, 64); lB += __shfl_xor(lB, 32, 64);
  // partial store (unnormalized): po[kh][bh][q][d] f16, pl[kh][bh*4096+q]
  _Float16* pobase = po + (size_t)kh * 2097152 + ((size_t)bh * S_LEN) * HDIM;
  {
    _Float16* poh = pobase + (size_t)(q0 + m) * HDIM;
    half4 h0 = { (_Float16)oA0[0], (_Float16)oA0[1], (_Float16)oA0[2], (_Float16)oA0[3] };
    half4 h1 = { (_Float16)oA1[0], (_Float16)oA1[1], (_Float16)oA1[2], (_Float16)oA1[3] };
    *(half4*)(poh + quad * 4) = h0;
    *(half4*)(poh + 16 + quad * 4) = h1;
    if (quad == 0) pl[(size_t)kh * 65536 + (size_t)bh * S_LEN + q0 + m] = lA;
  }
  {
    _Float16* poh = pobase + (size_t)(q0 + 16 + m) * HDIM;
    half4 h0 = { (_Float16)oB0[0], (_Float16)oB0[1], (_Float16)oB0[2], (_Float16)oB0[3] };
    half4 h1 = { (_Float16)oB1[0], (_Float16)oB1[1], (_Float16)oB1[2], (_Float16)oB1[3] };
    *(half4*)(poh + quad * 4) = h0;
    *(half4*)(poh + 16 + quad * 4) = h1;
    if (quad == 0) pl[(size_t)kh * 65536 + (size_t)bh * S_LEN + q0 + 16 + m] = lB;
  }
}

// ---------------------------------------------------------------- Proj GEMM (+ fused merge)
__global__ __launch_bounds__(256) void proj_gemm(
    const _Float16* __restrict__ W, const float* __restrict__ bias,
    const _Float16* __restrict__ po, const float* __restrict__ pl,
    const float* __restrict__ x, float* __restrict__ out)
{
  __shared__ float Linv[512];                // [n][s_local 64]
  const int tid = threadIdx.x;
  const int lane = tid & 63, wv = tid >> 6;
  const int m = lane & 15, quad = lane >> 4;
  const int mt = blockIdx.x * 4 + wv;  // 0..15
  const int s0 = blockIdx.y * 64;
  const int b = blockIdx.z;
  const int row = mt * 16 + m;

  {
    const int nn = tid >> 5, jj = (tid & 31) * 2;
    size_t base = (size_t)(b * NHEADS + nn) * S_LEN + s0 + jj;
    float a0 = pl[base]     + pl[65536 + base];
    float a1 = pl[base + 1] + pl[65536 + base + 1];
    Linv[nn * 64 + jj]     = 1.f / a0;
    Linv[nn * 64 + jj + 1] = 1.f / a1;
  }
  __syncthreads();

  const _Float16* wrow = W + (size_t)row * C_DIM + quad * 8;
  floatx4 acc0 = {0.f,0.f,0.f,0.f}, acc1 = acc0, acc2 = acc0, acc3 = acc0;
  #pragma unroll
  for (int k0 = 0; k0 < C_DIM; k0 += 32) {
    const int n = k0 >> 5;
    const int d0 = quad * 8;
    half8 bf[4];
    #pragma unroll
    for (int sub = 0; sub < 4; ++sub) {
      size_t idx = (((size_t)(b * NHEADS + n)) * S_LEN + s0 + sub * 16 + m) * HDIM + d0;
      half8 a = *(const half8*)(po + idx);
      half8 c = *(const half8*)(po + 2097152 + idx);
      _Float16 iv = (_Float16)Linv[n * 64 + sub * 16 + m];
      bf[sub] = (a + c) * iv;
    }
    half8 af = *(const half8*)(wrow + k0);
    acc0 = __builtin_amdgcn_mfma_f32_16x16x32_f16(af, bf[0], acc0, 0, 0, 0);
    acc1 = __builtin_amdgcn_mfma_f32_16x16x32_f16(af, bf[1], acc1, 0, 0, 0);
    acc2 = __builtin_amdgcn_mfma_f32_16x16x32_f16(af, bf[2], acc2, 0, 0, 0);
    acc3 = __builtin_amdgcn_mfma_f32_16x16x32_f16(af, bf[3], acc3, 0, 0, 0);
  }
  floatx4 accs[4] = {acc0, acc1, acc2, acc3};
  #pragma unroll
  for (int sub = 0; sub < 4; ++sub) {
    int s = s0 + sub * 16 + m;
    #pragma unroll
    for (int r = 0; r < 4; ++r) {
      int c = mt * 16 + quad * 4 + r;
      size_t idx = ((size_t)b * C_DIM + c) * S_LEN + s;
      out[idx] = x[idx] + accs[sub][r] + bias[c];
    }
  }
}

// ---------------------------------------------------------------- launch
extern "C" void kernel_launch(void* const* d_in, const int* in_sizes, int n_in,
                              void* d_out, int out_size, void* d_ws, size_t ws_size,
                              hipStream_t stream) {
  const float* x        = (const float*)d_in[0];
  const float* gn_gamma = (const float*)d_in[1];
  const float* gn_beta  = (const float*)d_in[2];
  const float* qkv_w    = (const float*)d_in[3];
  const float* qkv_b    = (const float*)d_in[4];
  const float* proj_w   = (const float*)d_in[5];
  const float* proj_b   = (const float*)d_in[6];
  float* out = (float*)d_out;

  const size_t n1 = (size_t)2 * S_LEN * C_DIM;   // 2M elems = 4 MB f16
  char* ws = (char*)d_ws;
  _Float16* qx  = (_Float16*)ws;                 // (B,NH,S,hd)
  _Float16* kx  = qx + n1;                       // (B,NH,S,hd)
  _Float16* vx  = kx + n1;                       // (B,NH,hd,S)
  _Float16* wq  = vx + n1;                       // 768x256 f16
  _Float16* wp  = wq + 768 * 256;                // 256x256 f16
  float*    qbias = (float*)(wp + 256 * 256);    // 768 f32
  float*    pstat = qbias + 768;                 // 64*8*2 f32 = 4 KB
  _Float16* po  = (_Float16*)(pstat + 1024);     // 2 x 2M f16 = 8 MB
  float*    pl  = (float*)(po + 2 * n1);         // 2 x 64K f32 = 512 KB

  prep_stats<<<1539, 256, 0, stream>>>(qkv_w, proj_w, qkv_b, x, wq, wp, qbias, pstat);
  qkv_gn_gemm<<<dim3(6, 64, 2), 256, 0, stream>>>(wq, qbias, x, gn_gamma, gn_beta, pstat, qx, kx, vx);
  attn_kernel<<<dim3(32, 8, 2), 512, 0, stream>>>(qx, kx, vx, po, pl);
  proj_gemm<<<dim3(4, 64, 2), 256, 0, stream>>>(wp, proj_b, po, pl, x, out);
}

// Round 4
// 144.015 us; speedup vs baseline: 1.0909x; 1.0300x over previous
//
#include <hip/hip_runtime.h>
#include <cstddef>

#define S_LEN 4096
#define C_DIM 256
#define NHEADS 8
#define HDIM 32

typedef __attribute__((ext_vector_type(8))) _Float16 half8;
typedef __attribute__((ext_vector_type(4))) _Float16 half4;
typedef __attribute__((ext_vector_type(2))) _Float16 h2t;
typedef __attribute__((ext_vector_type(2))) __fp16 fp16x2;
typedef __attribute__((ext_vector_type(4))) float floatx4;

// scale * log2(e) folded into W_q and bias_q at prep time
#define SC2F ((float)(0.17677669529663687 * 1.4426950408889634))

// ---------------------------------------------------------------- prep + GN partial stats
__global__ __launch_bounds__(256) void prep_stats(
    const float* __restrict__ qkv_w, const float* __restrict__ proj_w,
    const float* __restrict__ qkv_b, const float* __restrict__ x,
    _Float16* __restrict__ wq, _Float16* __restrict__ wp,
    float* __restrict__ qbias, float* __restrict__ pstat)
{
  const int blk = blockIdx.x;
  const int tid = threadIdx.x;
  if (blk < 512) {
    __shared__ float red[2][4];
    const int gb = blk >> 3, e = blk & 7;       // gb = b*32+g
    const int g = gb & 31, b = gb >> 5;
    const float* xb = x + ((size_t)b * C_DIM + g * 8) * S_LEN + e * 4096;
    const float4* x4 = (const float4*)xb;       // 1024 float4
    float sum = 0.f, sumsq = 0.f;
    #pragma unroll
    for (int i = 0; i < 4; ++i) {
      float4 v = x4[tid + i * 256];
      sum += v.x + v.y + v.z + v.w;
      sumsq += v.x * v.x + v.y * v.y + v.z * v.z + v.w * v.w;
    }
    for (int off = 1; off < 64; off <<= 1) {
      sum += __shfl_xor(sum, off, 64);
      sumsq += __shfl_xor(sumsq, off, 64);
    }
    const int wv = tid >> 6, lane = tid & 63;
    if (lane == 0) { red[0][wv] = sum; red[1][wv] = sumsq; }
    __syncthreads();
    if (tid == 0) {
      pstat[(gb * 8 + e) * 2 + 0] = red[0][0] + red[0][1] + red[0][2] + red[0][3];
      pstat[(gb * 8 + e) * 2 + 1] = red[1][0] + red[1][1] + red[1][2] + red[1][3];
    }
  } else {
    int idx = (blk - 512) * 256 + tid;
    if (idx < 768 * 256) {
      float v = qkv_w[idx];
      if (idx < 256 * 256) v *= SC2F;          // q rows
      wq[idx] = (_Float16)v;
    } else if (idx < 768 * 256 + 256 * 256) {
      int i = idx - 768 * 256;
      wp[i] = (_Float16)proj_w[i];
    } else if (idx < 768 * 256 + 256 * 256 + 768) {
      int i = idx - (768 * 256 + 256 * 256);
      float bv = qkv_b[i];
      if (i < 256) bv *= SC2F;
      qbias[i] = bv;
    }
  }
}

// ---------------------------------------------------------------- GN apply + transpose
// x (b,c,s) f32 -> xt (b,s,c) f16, normalized. One pass; qkv no longer
// re-reads/re-normalizes x 6x.
__global__ __launch_bounds__(256) void xnorm(
    const float* __restrict__ x, const float* __restrict__ gamma,
    const float* __restrict__ beta, const float* __restrict__ pstat,
    _Float16* __restrict__ xt)
{
  __shared__ _Float16 Lt[16][264];
  const int tid = threadIdx.x;
  const int b = blockIdx.y;
  const int s0 = blockIdx.x * 16;
  const int c = tid;
  const int gb = b * 32 + (c >> 3);
  float s = 0.f, sq = 0.f;
  #pragma unroll
  for (int e = 0; e < 8; ++e) {
    s  += pstat[(gb * 8 + e) * 2 + 0];
    sq += pstat[(gb * 8 + e) * 2 + 1];
  }
  const float mean = s * (1.f / 32768.f);
  const float rstd = rsqrtf(sq * (1.f / 32768.f) - mean * mean + 1e-6f);
  const float ga = gamma[c] * rstd, be = beta[c] - mean * ga;
  const float4* xa = (const float4*)(x + ((size_t)b * C_DIM + c) * S_LEN + s0);
  #pragma unroll
  for (int i = 0; i < 4; ++i) {
    float4 v = xa[i];
    Lt[i * 4 + 0][c] = (_Float16)(v.x * ga + be);
    Lt[i * 4 + 1][c] = (_Float16)(v.y * ga + be);
    Lt[i * 4 + 2][c] = (_Float16)(v.z * ga + be);
    Lt[i * 4 + 3][c] = (_Float16)(v.w * ga + be);
  }
  __syncthreads();
  const int sl = tid >> 4, cc = (tid & 15) * 16;
  _Float16* dst = xt + ((size_t)b * S_LEN + s0 + sl) * C_DIM + cc;
  const _Float16* src = &Lt[sl][cc];
  *(half8*)(dst + 0) = *(const half8*)(src + 0);
  *(half8*)(dst + 8) = *(const half8*)(src + 8);
}

// ---------------------------------------------------------------- QKV GEMM
// Reads pre-normalized xt (b,s,c) f16. grid.x 6->3 (xt read x3 instead of
// x-f32 x6), 4 mt tiles/wave (16/block). Block 0 -> q, 1 -> k, 2 -> v.
__global__ __launch_bounds__(256) void qkv_gemm(
    const _Float16* __restrict__ W, const float* __restrict__ bias,
    const _Float16* __restrict__ xt,
    _Float16* __restrict__ qo, _Float16* __restrict__ ko_,
    _Float16* __restrict__ vo)
{
  __shared__ __align__(16) _Float16 Ld[256 * 72];   // >= 64*264; v-stage 256*72
  const int tid = threadIdx.x;
  const int b = blockIdx.z;
  const int s0 = blockIdx.y * 64;

  {  // ---- stage xt[s0..+64][0..256] -> Ld[s][c] (stride 264), pure copy
    const int sl = tid >> 2, cc = (tid & 3) * 64;
    const _Float16* src = xt + ((size_t)b * S_LEN + s0 + sl) * C_DIM + cc;
    _Float16* dst = &Ld[sl * 264 + cc];
    #pragma unroll
    for (int j = 0; j < 8; ++j)
      *(half8*)(dst + j * 8) = *(const half8*)(src + j * 8);
  }
  __syncthreads();

  const int lane = tid & 63, wv = tid >> 6;
  const int m = lane & 15, quad = lane >> 4;
  const int mtb = blockIdx.x * 16 + wv * 4;     // 4 mt tiles per wave
  const _Float16* wrow[4];
  #pragma unroll
  for (int j = 0; j < 4; ++j)
    wrow[j] = W + (size_t)((mtb + j) * 16 + m) * C_DIM + quad * 8;
  const _Float16* lp = &Ld[m * 264 + quad * 8];

  floatx4 acc[4][4];
  #pragma unroll
  for (int j = 0; j < 4; ++j)
    #pragma unroll
    for (int s = 0; s < 4; ++s) acc[j][s] = (floatx4){0.f,0.f,0.f,0.f};

  #pragma unroll 2
  for (int k0 = 0; k0 < C_DIM; k0 += 32) {
    half8 b0 = *(const half8*)(lp + k0);
    half8 b1 = *(const half8*)(lp + 16 * 264 + k0);
    half8 b2 = *(const half8*)(lp + 32 * 264 + k0);
    half8 b3 = *(const half8*)(lp + 48 * 264 + k0);
    #pragma unroll
    for (int j = 0; j < 4; ++j) {
      half8 a = *(const half8*)(wrow[j] + k0);
      acc[j][0] = __builtin_amdgcn_mfma_f32_16x16x32_f16(a, b0, acc[j][0], 0, 0, 0);
      acc[j][1] = __builtin_amdgcn_mfma_f32_16x16x32_f16(a, b1, acc[j][1], 0, 0, 0);
      acc[j][2] = __builtin_amdgcn_mfma_f32_16x16x32_f16(a, b2, acc[j][2], 0, 0, 0);
      acc[j][3] = __builtin_amdgcn_mfma_f32_16x16x32_f16(a, b3, acc[j][3], 0, 0, 0);
    }
  }

  if (blockIdx.x < 2) {
    // ---- q/k epilogue: coalesced half4 stores
    #pragma unroll
    for (int j = 0; j < 4; ++j) {
      const int ob = (mtb + j) * 16 + quad * 4;
      const float bv0 = bias[ob], bv1 = bias[ob + 1],
                  bv2 = bias[ob + 2], bv3 = bias[ob + 3];
      _Float16* dst = (ob < 256) ? qo : ko_;
      const int oo = ob & 255, n = oo >> 5, d0 = oo & 31;
      #pragma unroll
      for (int sub = 0; sub < 4; ++sub) {
        int s = s0 + sub * 16 + m;
        half4 h = { (_Float16)(acc[j][sub][0] + bv0), (_Float16)(acc[j][sub][1] + bv1),
                    (_Float16)(acc[j][sub][2] + bv2), (_Float16)(acc[j][sub][3] + bv3) };
        *(half4*)(dst + (((size_t)b * NHEADS + n) * S_LEN + s) * HDIM + d0) = h;
      }
    }
  } else {
    // ---- v epilogue via LDS: stage [256 ch][64 s] (stride 72)
    __syncthreads();                          // Ld b-frag reads complete
    _Float16* VLd = Ld;                       // reuse, 256*72*2B = 36.9 KB
    #pragma unroll
    for (int j = 0; j < 4; ++j) {
      const int ob = (mtb + j) * 16 + quad * 4;
      const int lch = (wv * 4 + j) * 16 + quad * 4;   // 0..255
      const float bv0 = bias[ob], bv1 = bias[ob + 1],
                  bv2 = bias[ob + 2], bv3 = bias[ob + 3];
      #pragma unroll
      for (int sub = 0; sub < 4; ++sub) {
        int s = sub * 16 + m;
        VLd[(lch + 0) * 72 + s] = (_Float16)(acc[j][sub][0] + bv0);
        VLd[(lch + 1) * 72 + s] = (_Float16)(acc[j][sub][1] + bv1);
        VLd[(lch + 2) * 72 + s] = (_Float16)(acc[j][sub][2] + bv2);
        VLd[(lch + 3) * 72 + s] = (_Float16)(acc[j][sub][3] + bv3);
      }
    }
    __syncthreads();
    // coalesced store: pass p covers ch p*32..+32; 8 lanes per ch
    const int sh3 = tid & 7, chl = tid >> 3;  // chl 0..31
    #pragma unroll
    for (int p = 0; p < 8; ++p) {
      const int ch = p * 32 + chl;            // 0..255
      const int n = ch >> 5, d = ch & 31;
      _Float16* dst = vo + ((size_t)(b * NHEADS + n) * HDIM + d) * S_LEN + s0 + sh3 * 8;
      *(half8*)dst = *(const half8*)(VLd + ch * 72 + sh3 * 8);
    }
  }
}

// ---------------------------------------------------------------- Attention
// R3 state (unchanged): 128-key tiles, per-wave phase rotation, setprio.
__global__ __launch_bounds__(512) void attn_kernel(
    const _Float16* __restrict__ q, const _Float16* __restrict__ k,
    const _Float16* __restrict__ v, _Float16* __restrict__ po,
    float* __restrict__ pl)
{
  __shared__ __align__(16) _Float16 Kl[2][128 * 40];  // (kk, d) stride 40
  __shared__ __align__(16) _Float16 Vl[2][32 * 136];  // (d, kk) stride 136
  const int tid = threadIdx.x;
  const int lane = tid & 63, wv = tid >> 6;          // wv 0..7
  const int m = lane & 15, quad = lane >> 4;
  const int n = blockIdx.y, b = blockIdx.z;
  const int qc = blockIdx.x >> 1, kh = blockIdx.x & 1;
  const int q0 = qc * 256 + wv * 32;
  const int bh = b * NHEADS + n;

  const _Float16* qb = q + (size_t)bh * S_LEN * HDIM;
  const _Float16* kb = k + (size_t)bh * S_LEN * HDIM + (size_t)kh * 2048 * HDIM;
  const _Float16* vb = v + (size_t)bh * HDIM * S_LEN + (size_t)kh * 2048;

  half8 qfA = *(const half8*)(qb + (size_t)(q0 + m) * HDIM + quad * 8);
  half8 qfB = *(const half8*)(qb + (size_t)(q0 + 16 + m) * HDIM + quad * 8);

  const int krow = wv * 16 + (lane >> 2), kc = (lane & 3) * 8;
  const int vrow = wv * 4 + (lane >> 4), vc = (lane & 15) * 8;
  const _Float16* kg = kb + (size_t)krow * HDIM + kc;
  const _Float16* vg = vb + (size_t)vrow * S_LEN + vc;
  const int klds = krow * 40 + kc;
  const int vlds = vrow * 136 + vc;

  int4 kreg = *(const int4*)kg;
  int4 vreg = *(const int4*)vg;
  const _Float16* kgp = kg + 128 * HDIM;
  const _Float16* vgp = vg + 128;

  floatx4 oA0 = {0.f,0.f,0.f,0.f}, oA1 = oA0, oB0 = oA0, oB1 = oA0;
  float lA0 = 0.f, lA1 = 0.f, lB0 = 0.f, lB1 = 0.f;
  const fp16x2 one2 = { (__fp16)1.0f, (__fp16)1.0f };
  const floatx4 zz = {0.f,0.f,0.f,0.f};

  #pragma unroll 2
  for (int it = 0; it < 16; ++it) {          // 16 x 128 keys = 2048 (half)
    const int bufi = it & 1;
    *(int4*)(&Kl[bufi][klds]) = kreg;
    *(int4*)(&Vl[bufi][vlds]) = vreg;
    kreg = *(const int4*)kgp; kgp += 128 * HDIM;   // unconditional prefetch
    vreg = *(const int4*)vgp; vgp += 128;
    __syncthreads();
    const _Float16* Kb = Kl[bufi];
    const _Float16* Vb = Vl[bufi];

    #pragma unroll
    for (int t = 0; t < 8; ++t) {
      const int tt = (t + wv) & 7;           // per-wave phase rotation
      half8 kf  = *(const half8*)(Kb + (tt * 16 + m) * 40 + quad * 8);
      half4 vf0 = *(const half4*)(Vb + m * 136 + tt * 16 + quad * 4);
      half4 vf1 = *(const half4*)(Vb + (16 + m) * 136 + tt * 16 + quad * 4);
      __builtin_amdgcn_s_setprio(1);
      floatx4 sA = __builtin_amdgcn_mfma_f32_16x16x32_f16(kf, qfA, zz, 0, 0, 0);
      floatx4 sB = __builtin_amdgcn_mfma_f32_16x16x32_f16(kf, qfB, zz, 0, 0, 0);
      __builtin_amdgcn_s_setprio(0);
      float eA0 = __builtin_amdgcn_exp2f(sA[0]);
      float eA1 = __builtin_amdgcn_exp2f(sA[1]);
      float eA2 = __builtin_amdgcn_exp2f(sA[2]);
      float eA3 = __builtin_amdgcn_exp2f(sA[3]);
      float eB0 = __builtin_amdgcn_exp2f(sB[0]);
      float eB1 = __builtin_amdgcn_exp2f(sB[1]);
      float eB2 = __builtin_amdgcn_exp2f(sB[2]);
      float eB3 = __builtin_amdgcn_exp2f(sB[3]);
      half4 pA, pB;
      fp16x2 pAlo = __builtin_amdgcn_cvt_pkrtz(eA0, eA1);
      fp16x2 pAhi = __builtin_amdgcn_cvt_pkrtz(eA2, eA3);
      fp16x2 pBlo = __builtin_amdgcn_cvt_pkrtz(eB0, eB1);
      fp16x2 pBhi = __builtin_amdgcn_cvt_pkrtz(eB2, eB3);
      *(fp16x2*)&pA = pAlo; *((fp16x2*)&pA + 1) = pAhi;
      *(fp16x2*)&pB = pBlo; *((fp16x2*)&pB + 1) = pBhi;
      lA0 = __builtin_amdgcn_fdot2(pAlo, one2, lA0, false);
      lA1 = __builtin_amdgcn_fdot2(pAhi, one2, lA1, false);
      lB0 = __builtin_amdgcn_fdot2(pBlo, one2, lB0, false);
      lB1 = __builtin_amdgcn_fdot2(pBhi, one2, lB1, false);
      __builtin_amdgcn_s_setprio(1);
      oA0 = __builtin_amdgcn_mfma_f32_16x16x16f16(vf0, pA, oA0, 0, 0, 0);
      oA1 = __builtin_amdgcn_mfma_f32_16x16x16f16(vf1, pA, oA1, 0, 0, 0);
      oB0 = __builtin_amdgcn_mfma_f32_16x16x16f16(vf0, pB, oB0, 0, 0, 0);
      oB1 = __builtin_amdgcn_mfma_f32_16x16x16f16(vf1, pB, oB1, 0, 0, 0);
      __builtin_amdgcn_s_setprio(0);
    }
  }
  float lA = lA0 + lA1, lB = lB0 + lB1;
  lA += __shfl_xor(lA, 16, 64); lA += __shfl_xor(lA, 32, 64);
  lB += __shfl_xor(lB, 16, 64); lB += __shfl_xor(lB, 32, 64);
  _Float16* pobase = po + (size_t)kh * 2097152 + ((size_t)bh * S_LEN) * HDIM;
  {
    _Float16* poh = pobase + (size_t)(q0 + m) * HDIM;
    half4 h0 = { (_Float16)oA0[0], (_Float16)oA0[1], (_Float16)oA0[2], (_Float16)oA0[3] };
    half4 h1 = { (_Float16)oA1[0], (_Float16)oA1[1], (_Float16)oA1[2], (_Float16)oA1[3] };
    *(half4*)(poh + quad * 4) = h0;
    *(half4*)(poh + 16 + quad * 4) = h1;
    if (quad == 0) pl[(size_t)kh * 65536 + (size_t)bh * S_LEN + q0 + m] = lA;
  }
  {
    _Float16* poh = pobase + (size_t)(q0 + 16 + m) * HDIM;
    half4 h0 = { (_Float16)oB0[0], (_Float16)oB0[1], (_Float16)oB0[2], (_Float16)oB0[3] };
    half4 h1 = { (_Float16)oB1[0], (_Float16)oB1[1], (_Float16)oB1[2], (_Float16)oB1[3] };
    *(half4*)(poh + quad * 4) = h0;
    *(half4*)(poh + 16 + quad * 4) = h1;
    if (quad == 0) pl[(size_t)kh * 65536 + (size_t)bh * S_LEN + q0 + 16 + m] = lB;
  }
}

// ---------------------------------------------------------------- Proj GEMM (+ fused merge)
// grid.x 4->2, 2 mt tiles/wave: po read x2 (was x4), merge-VALU amortized
// across both mt tiles.
__global__ __launch_bounds__(256) void proj_gemm(
    const _Float16* __restrict__ W, const float* __restrict__ bias,
    const _Float16* __restrict__ po, const float* __restrict__ pl,
    const float* __restrict__ x, float* __restrict__ out)
{
  __shared__ float Linv[512];                // [n][s_local 64]
  const int tid = threadIdx.x;
  const int lane = tid & 63, wv = tid >> 6;
  const int m = lane & 15, quad = lane >> 4;
  const int mtb = blockIdx.x * 8 + wv * 2;   // 2 mt tiles per wave
  const int s0 = blockIdx.y * 64;
  const int b = blockIdx.z;

  {
    const int nn = tid >> 5, jj = (tid & 31) * 2;
    size_t base = (size_t)(b * NHEADS + nn) * S_LEN + s0 + jj;
    float a0 = pl[base]     + pl[65536 + base];
    float a1 = pl[base + 1] + pl[65536 + base + 1];
    Linv[nn * 64 + jj]     = 1.f / a0;
    Linv[nn * 64 + jj + 1] = 1.f / a1;
  }
  __syncthreads();

  const _Float16* wrow0 = W + (size_t)((mtb + 0) * 16 + m) * C_DIM + quad * 8;
  const _Float16* wrow1 = W + (size_t)((mtb + 1) * 16 + m) * C_DIM + quad * 8;
  floatx4 acc[2][4];
  #pragma unroll
  for (int j = 0; j < 2; ++j)
    #pragma unroll
    for (int s = 0; s < 4; ++s) acc[j][s] = (floatx4){0.f,0.f,0.f,0.f};

  #pragma unroll
  for (int k0 = 0; k0 < C_DIM; k0 += 32) {
    const int n = k0 >> 5;
    const int d0 = quad * 8;
    half8 bf[4];
    #pragma unroll
    for (int sub = 0; sub < 4; ++sub) {
      size_t idx = (((size_t)(b * NHEADS + n)) * S_LEN + s0 + sub * 16 + m) * HDIM + d0;
      half8 a = *(const half8*)(po + idx);
      half8 c = *(const half8*)(po + 2097152 + idx);
      _Float16 iv = (_Float16)Linv[n * 64 + sub * 16 + m];
      bf[sub] = (a + c) * iv;
    }
    half8 af0 = *(const half8*)(wrow0 + k0);
    half8 af1 = *(const half8*)(wrow1 + k0);
    #pragma unroll
    for (int sub = 0; sub < 4; ++sub) {
      acc[0][sub] = __builtin_amdgcn_mfma_f32_16x16x32_f16(af0, bf[sub], acc[0][sub], 0, 0, 0);
      acc[1][sub] = __builtin_amdgcn_mfma_f32_16x16x32_f16(af1, bf[sub], acc[1][sub], 0, 0, 0);
    }
  }
  #pragma unroll
  for (int j = 0; j < 2; ++j)
    #pragma unroll
    for (int sub = 0; sub < 4; ++sub) {
      int s = s0 + sub * 16 + m;
      #pragma unroll
      for (int r = 0; r < 4; ++r) {
        int c = (mtb + j) * 16 + quad * 4 + r;
        size_t idx = ((size_t)b * C_DIM + c) * S_LEN + s;
        out[idx] = x[idx] + acc[j][sub][r] + bias[c];
      }
    }
}

// ---------------------------------------------------------------- launch
extern "C" void kernel_launch(void* const* d_in, const int* in_sizes, int n_in,
                              void* d_out, int out_size, void* d_ws, size_t ws_size,
                              hipStream_t stream) {
  const float* x        = (const float*)d_in[0];
  const float* gn_gamma = (const float*)d_in[1];
  const float* gn_beta  = (const float*)d_in[2];
  const float* qkv_w    = (const float*)d_in[3];
  const float* qkv_b    = (const float*)d_in[4];
  const float* proj_w   = (const float*)d_in[5];
  const float* proj_b   = (const float*)d_in[6];
  float* out = (float*)d_out;

  const size_t n1 = (size_t)2 * S_LEN * C_DIM;   // 2M elems = 4 MB f16
  char* ws = (char*)d_ws;
  _Float16* qx  = (_Float16*)ws;                 // (B,NH,S,hd)
  _Float16* kx  = qx + n1;                       // (B,NH,S,hd)
  _Float16* vx  = kx + n1;                       // (B,NH,hd,S)
  _Float16* wq  = vx + n1;                       // 768x256 f16
  _Float16* wp  = wq + 768 * 256;                // 256x256 f16
  float*    qbias = (float*)(wp + 256 * 256);    // 768 f32
  float*    pstat = qbias + 768;                 // 64*8*2 f32 = 4 KB
  _Float16* po  = (_Float16*)(pstat + 1024);     // 2 x 2M f16 = 8 MB
  float*    pl  = (float*)(po + 2 * n1);         // 2 x 64K f32 = 512 KB
  _Float16* xt  = (_Float16*)(pl + 2 * 65536);   // (B,S,C) f16 = 4.2 MB

  prep_stats<<<1539, 256, 0, stream>>>(qkv_w, proj_w, qkv_b, x, wq, wp, qbias, pstat);
  xnorm<<<dim3(256, 2), 256, 0, stream>>>(x, gn_gamma, gn_beta, pstat, xt);
  qkv_gemm<<<dim3(3, 64, 2), 256, 0, stream>>>(wq, qbias, xt, qx, kx, vx);
  attn_kernel<<<dim3(32, 8, 2), 512, 0, stream>>>(qx, kx, vx, po, pl);
  proj_gemm<<<dim3(2, 64, 2), 256, 0, stream>>>(wp, proj_b, po, pl, x, out);
}